// Round 1
// baseline (538.124 us; speedup 1.0000x reference)
//
#include <hip/hip_runtime.h>

#define N_NODES 100000
#define N_EDGES 6400000
#define IN_CH 14
#define HID 16
#define OUT_CH 8

#define NBINS 1024
#define BINW 98             // 1024*98 = 100352 >= 100000
#define NCLS 8              // XCD classes (blockIdx & 7)
#define SLABC 1152          // words per (bin,class); mean 781, sigma ~28 (13-sigma cap)
#define BINREG (NCLS * SLABC)                  // 9216 words per bin region
#define BINBUF_WORDS (NBINS * BINREG)          // 9,437,184
#define SORT_CAP 7168       // LDS staging cap per bin; mean 6250, sigma ~79
#define BF_THREADS 1024
#define BF_TILE 8192
#define BF_EPT (BF_TILE / BF_THREADS)          // 8 edges/thread
#define N_TILES ((N_EDGES + BF_TILE - 1) / BF_TILE)   // 782
#define LHN 128             // pow2 >= BINW for the per-bin scan

// round-to-nearest-even fp32 -> bf16 (as ushort)
__device__ __forceinline__ unsigned short f2bf(float f) {
    unsigned u = __float_as_uint(f);
    u += 0x7fffu + ((u >> 16) & 1u);
    return (unsigned short)(u >> 16);
}

// ---------------------------------------------------------------------------
// prep: cast x to padded bf16 rows (16 ushorts, pad=0) AND zero the 8x1024
// tail counters and the global per-node degree array (workspace is
// 0xAA-poisoned before every launch).
// ---------------------------------------------------------------------------
__global__ void prep_kernel(const float* __restrict__ x, unsigned short* __restrict__ xb,
                            int* __restrict__ tail, int* __restrict__ deg) {
    int i = blockIdx.x * blockDim.x + threadIdx.x;
    if (i < NCLS * NBINS) tail[i] = 0;
    if (i < NBINS * BINW) deg[i] = 0;          // binfill atomics accumulate into this
    if (i >= (NBINS * BINW) * 16) return;
    int n = i >> 4, c = i & 15;
    float v = (n < N_NODES && c < IN_CH) ? x[n * IN_CH + c] : 0.0f;
    xb[i] = f2bf(v);
}

// ---------------------------------------------------------------------------
// binfill: per 8192-edge tile, LDS counting-sort by bin, reserve a dense
// chunk in the bin's CLASS sub-slab (class = blockIdx&7 ~ XCD) via one tail
// atomic, then LINEAR write-out. Same-class tiles write adjacent chunks ->
// each 64B line is produced by ~one XCD -> minimal write amplification.
// Packed word: src [0,17) | local dst [17,24).
// NEW: also accumulates the global per-node degree via fire-and-forget
// global atomics (deg is 400 KB, L2-resident, ~64 hits/address) so that
// sortagg1 no longer needs its histogram pass over binbuf.
// ---------------------------------------------------------------------------
__global__ __launch_bounds__(BF_THREADS)
void binfill_kernel(const uint4* __restrict__ src4, const uint4* __restrict__ dst4,
                    int* __restrict__ tail, unsigned* __restrict__ binbuf,
                    int* __restrict__ deg) {
    __shared__ unsigned stile[BF_TILE];        // 32 KB sorted packed words
    __shared__ unsigned short stbin[BF_TILE];  // 16 KB bin id per sorted slot
    __shared__ int lh[NBINS];                  // 4 KB tile histogram
    __shared__ int lx[NBINS];                  // 4 KB exclusive offsets
    __shared__ int lofs[NBINS];                // 4 KB reserved sub-slab offsets
    __shared__ int wsum[16];

    const int t = threadIdx.x;
    const int lane = t & 63;
    const int wv = t >> 6;                     // 16 waves
    const int cls = blockIdx.x & (NCLS - 1);
    const long long tb = (long long)blockIdx.x * BF_TILE;

    lh[t] = 0;                                 // BF_THREADS == NBINS
    __syncthreads();

    unsigned epack[BF_EPT];
    int      ebin[BF_EPT];
    int      erank[BF_EPT];

#pragma unroll
    for (int sw = 0; sw < BF_EPT / 4; ++sw) {
        long long u = tb / 4 + (long long)sw * BF_THREADS + t;
        int k = sw * 4;
        if (u * 4 < N_EDGES) {
            uint4 s = src4[u];
            uint4 d = dst4[u];
            unsigned b;
            b = d.x / BINW; epack[k+0] = s.x | ((d.x - b*BINW) << 17); ebin[k+0] = (int)b; erank[k+0] = atomicAdd(&lh[b], 1);
            b = d.y / BINW; epack[k+1] = s.y | ((d.y - b*BINW) << 17); ebin[k+1] = (int)b; erank[k+1] = atomicAdd(&lh[b], 1);
            b = d.z / BINW; epack[k+2] = s.z | ((d.z - b*BINW) << 17); ebin[k+2] = (int)b; erank[k+2] = atomicAdd(&lh[b], 1);
            b = d.w / BINW; epack[k+3] = s.w | ((d.w - b*BINW) << 17); ebin[k+3] = (int)b; erank[k+3] = atomicAdd(&lh[b], 1);
            // global per-node degree (no return value -> no wait)
            atomicAdd(&deg[d.x], 1);
            atomicAdd(&deg[d.y], 1);
            atomicAdd(&deg[d.z], 1);
            atomicAdd(&deg[d.w], 1);
        } else {
            ebin[k+0] = ebin[k+1] = ebin[k+2] = ebin[k+3] = -1;
        }
    }
    __syncthreads();

    // wave-level exclusive scan of lh (1024 entries, 16 waves)
    int v = lh[t];
    int incl = v;
#pragma unroll
    for (int d = 1; d < 64; d <<= 1) {
        int o = __shfl_up(incl, d, 64);
        if (lane >= d) incl += o;
    }
    if (lane == 63) wsum[wv] = incl;
    __syncthreads();
    if (t < 16) {
        int s = wsum[t];
        int si = s;
#pragma unroll
        for (int d = 1; d < 16; d <<= 1) {
            int o = __shfl_up(si, d, 16);
            if (t >= d) si += o;
        }
        wsum[t] = si - s;                      // exclusive wave offset
    }
    __syncthreads();
    lx[t] = incl - v + wsum[wv];               // exclusive within tile
    lofs[t] = atomicAdd(&tail[cls * NBINS + t], v);   // offset within sub-slab
    __syncthreads();

    // place into LDS sorted-by-bin order
#pragma unroll
    for (int k = 0; k < BF_EPT; ++k) {
        if (ebin[k] >= 0) {
            int pos = lx[ebin[k]] + erank[k];
            stile[pos] = epack[k];
            stbin[pos] = (unsigned short)ebin[k];
        }
    }
    __syncthreads();

    // linear coalesced write-out into per-(bin,class) sub-slabs
    int cnt = (int)((N_EDGES - tb < BF_TILE) ? (N_EDGES - tb) : BF_TILE);
    for (int i = t; i < cnt; i += BF_THREADS) {
        int b = stbin[i];
        int slot = lofs[b] + (i - lx[b]);
        if ((unsigned)slot < (unsigned)SLABC)  // deterministic: never overflows
            binbuf[b * BINREG + cls * SLABC + slot] = stile[i];
    }
}

// ---------------------------------------------------------------------------
// FUSED bin-local counting sort + layer-1 aggregation. One block per bin:
// 1024 blocks, 512 threads, ~30 KB LDS -> 4 blocks/CU (32 waves).
// The histogram pass over binbuf is GONE: per-node degrees come from the
// global deg array accumulated by binfill. One fewer 25.6 MB segment pass,
// 6.4M fewer LDS atomics, one fewer barrier phase. P0's serial 8 global
// loads replaced by 8 parallel loads + LDS-only serial scan.
// ---------------------------------------------------------------------------
__global__ __launch_bounds__(512)
void sortagg1_kernel(const unsigned* __restrict__ xb, const float* __restrict__ x,
                     unsigned* __restrict__ binbuf, const int* __restrict__ tail,
                     int* __restrict__ rowptr, const int* __restrict__ deg,
                     const float* __restrict__ W_l, const float* __restrict__ bias,
                     const float* __restrict__ W_r,
                     float* __restrict__ h_f32, unsigned short* __restrict__ h_bf16) {
    __shared__ unsigned sbuf[SORT_CAP];   // 28,672 B; overlaid by smean in P6
    __shared__ int lhist[LHN];
    __shared__ int loff[LHN];
    __shared__ int lcur[LHN];
    __shared__ int wtot[2];
    __shared__ int segcnt[NCLS];
    __shared__ int totc[1];

    const int b = blockIdx.x;
    const int t = threadIdx.x;
    const int regbase = b * BINREG;

    // P0a: per-class segment counts loaded in parallel (coalesced-ish, 8 lanes)
    if (t < NCLS) {
        int c = tail[t * NBINS + b];
        if (c < 0) c = 0;
        if (c > SLABC) c = SLABC;
        segcnt[t] = c;
    }

    // P2a: per-node degree straight from global (written by binfill atomics)
    int v = 0;
    if (t < LHN) {
        int gn = b * BINW + t;
        if (t < BINW && gn < N_NODES) v = deg[gn];
        lhist[t] = v;                          // P5 reads lhist[n] as the degree
    }

    // P2b: wave-level exclusive scan of 128 entries
    int incl = v;
#pragma unroll
    for (int d = 1; d < 64; d <<= 1) {
        int o = __shfl_up(incl, d, 64);
        if ((t & 63) >= d) incl += o;
    }
    if (t < LHN && (t & 63) == 63) wtot[t >> 6] = incl;

    // P0b: segment offsets; lane 0 of wave 0 — segcnt writes (lanes 0-7 of
    // this same wave) precede in program order, no barrier needed.
    if (t == 0) {
        int s = 0;
        for (int k = 0; k < NCLS; ++k) {
            int c = segcnt[k];
            if (s + c > SORT_CAP) { c = SORT_CAP - s; segcnt[k] = c; }  // insurance
            s += c;
        }
        totc[0] = s;
    }
    __syncthreads();
    const int cnt = totc[0];

    if (t < LHN) {
        int excl = incl - v + ((t >= 64) ? wtot[0] : 0);
        loff[t] = excl;
        lcur[t] = excl;
        if (t < BINW) {
            int gn = b * BINW + t;
            if (gn < N_NODES) rowptr[gn] = regbase + excl;   // deg already global
        }
    }
    __syncthreads();

    // P3: rank & place sorted src into LDS (global read is L2-hot post-binfill)
    for (int k = 0; k < NCLS; ++k) {
        const int base = regbase + k * SLABC;
        const int c = segcnt[k];
        for (int i = t; i < c; i += 512) {
            unsigned w = binbuf[base + i];
            unsigned ld = w >> 17;
            int pos = atomicAdd(&lcur[ld], 1);
            if (pos < cnt) sbuf[pos] = w & 0x1FFFFu;
        }
    }
    __syncthreads();

    // P4: coalesced copy-out of sorted csr (contiguous from region start)
    for (int i = t; i < cnt; i += 512)
        binbuf[regbase + i] = sbuf[i];

    // P5: gather. 64 groups of 8 lanes; lane l holds channels 2l, 2l+1.
    const int g = t >> 3;
    const int l = t & 7;
    float m0[2], m1[2];
#pragma unroll
    for (int p = 0; p < 2; ++p) {
        m0[p] = 0.0f; m1[p] = 0.0f;
        int n = g + 64 * p;
        if (n < BINW) {
            int dg = lhist[n];
            int off = loff[n];
            float a0 = 0.0f, a1 = 0.0f;
            int i = 0;
            for (; i + 4 <= dg; i += 4) {
                unsigned s0 = sbuf[off + i], s1 = sbuf[off + i + 1];
                unsigned s2 = sbuf[off + i + 2], s3 = sbuf[off + i + 3];
                unsigned u0 = xb[s0 * 8 + l];
                unsigned u1 = xb[s1 * 8 + l];
                unsigned u2 = xb[s2 * 8 + l];
                unsigned u3 = xb[s3 * 8 + l];
                a0 += __uint_as_float(u0 << 16);  a1 += __uint_as_float(u0 & 0xffff0000u);
                a0 += __uint_as_float(u1 << 16);  a1 += __uint_as_float(u1 & 0xffff0000u);
                a0 += __uint_as_float(u2 << 16);  a1 += __uint_as_float(u2 & 0xffff0000u);
                a0 += __uint_as_float(u3 << 16);  a1 += __uint_as_float(u3 & 0xffff0000u);
            }
            for (; i < dg; ++i) {
                unsigned u0 = xb[sbuf[off + i] * 8 + l];
                a0 += __uint_as_float(u0 << 16);  a1 += __uint_as_float(u0 & 0xffff0000u);
            }
            float inv = 1.0f / fmaxf((float)dg, 1.0f);
            m0[p] = a0 * inv; m1[p] = a1 * inv;
        }
    }
    __syncthreads();                 // all sbuf reads done -> safe to overlay

    // P6: overlay means, fused MLP epilogue
    float* smean = (float*)sbuf;     // 98*16 floats = 6,272 B < SORT_CAP*4
#pragma unroll
    for (int p = 0; p < 2; ++p) {
        int n = g + 64 * p;
        if (n < BINW) {
            smean[n * 16 + 2 * l]     = m0[p];
            smean[n * 16 + 2 * l + 1] = m1[p];
        }
    }
    __syncthreads();

    const int nodeBase = b * BINW;
    for (int i = t; i < BINW * HID; i += 512) {
        int n = i >> 4, oc = i & 15;
        int gn = nodeBase + n;
        if (gn >= N_NODES) break;
        float a = bias[oc];
#pragma unroll
        for (int k = 0; k < IN_CH; ++k)
            a = fmaf(smean[n * 16 + k], W_l[oc * IN_CH + k],
                     fmaf(x[gn * IN_CH + k], W_r[oc * IN_CH + k], a));
        float vv = fmaxf(a, 0.0f);
        h_f32[gn * HID + oc] = vv;
        h_bf16[gn * HID + oc] = f2bf(vv);
    }
}

// ---------------------------------------------------------------------------
// Layer 2 aggregation: no atomics, register accumulation, 8 lanes/node over
// sorted csr; bf16 gather table, fp32 root term; 8x unroll.
// ---------------------------------------------------------------------------
__global__ __launch_bounds__(256)
void agg2_kernel(const unsigned* __restrict__ hb,
                 const float* __restrict__ h_f32,
                 const unsigned* __restrict__ csr,
                 const int* __restrict__ rowptr, const int* __restrict__ deg,
                 const float* __restrict__ W_l, const float* __restrict__ bias,
                 const float* __restrict__ W_r, float* __restrict__ out) {
    __shared__ float smean[4][8][16];

    const int t = threadIdx.x;
    const int wv = t >> 6;
    const int lane = t & 63;
    const int g = lane >> 3;
    const int l = lane & 7;
    const int node = (blockIdx.x * 4 + wv) * 8 + g;

    int beg = rowptr[node];
    int d = deg[node];
    if (beg < 0) beg = 0;
    if (d < 0) d = 0;
    if (beg + d > BINBUF_WORDS) d = BINBUF_WORDS - beg;

    float a0 = 0.0f, a1 = 0.0f;
    int i = 0;
    for (; i + 8 <= d; i += 8) {
        unsigned s0 = csr[beg + i]     & 0x1FFFFu;
        unsigned s1 = csr[beg + i + 1] & 0x1FFFFu;
        unsigned s2 = csr[beg + i + 2] & 0x1FFFFu;
        unsigned s3 = csr[beg + i + 3] & 0x1FFFFu;
        unsigned s4 = csr[beg + i + 4] & 0x1FFFFu;
        unsigned s5 = csr[beg + i + 5] & 0x1FFFFu;
        unsigned s6 = csr[beg + i + 6] & 0x1FFFFu;
        unsigned s7 = csr[beg + i + 7] & 0x1FFFFu;
        unsigned u0 = hb[s0 * 8 + l];
        unsigned u1 = hb[s1 * 8 + l];
        unsigned u2 = hb[s2 * 8 + l];
        unsigned u3 = hb[s3 * 8 + l];
        unsigned u4 = hb[s4 * 8 + l];
        unsigned u5 = hb[s5 * 8 + l];
        unsigned u6 = hb[s6 * 8 + l];
        unsigned u7 = hb[s7 * 8 + l];
        a0 += __uint_as_float(u0 << 16);        a1 += __uint_as_float(u0 & 0xffff0000u);
        a0 += __uint_as_float(u1 << 16);        a1 += __uint_as_float(u1 & 0xffff0000u);
        a0 += __uint_as_float(u2 << 16);        a1 += __uint_as_float(u2 & 0xffff0000u);
        a0 += __uint_as_float(u3 << 16);        a1 += __uint_as_float(u3 & 0xffff0000u);
        a0 += __uint_as_float(u4 << 16);        a1 += __uint_as_float(u4 & 0xffff0000u);
        a0 += __uint_as_float(u5 << 16);        a1 += __uint_as_float(u5 & 0xffff0000u);
        a0 += __uint_as_float(u6 << 16);        a1 += __uint_as_float(u6 & 0xffff0000u);
        a0 += __uint_as_float(u7 << 16);        a1 += __uint_as_float(u7 & 0xffff0000u);
    }
    for (; i < d; ++i) {
        unsigned s0 = csr[beg + i] & 0x1FFFFu;
        unsigned u0 = hb[s0 * 8 + l];
        a0 += __uint_as_float(u0 << 16);        a1 += __uint_as_float(u0 & 0xffff0000u);
    }
    float inv = 1.0f / fmaxf((float)d, 1.0f);
    smean[wv][g][2 * l]     = a0 * inv;
    smean[wv][g][2 * l + 1] = a1 * inv;

    {
        int n8 = lane >> 3;
        int oc = lane & 7;
        int gn = (blockIdx.x * 4 + wv) * 8 + n8;
        float a = bias[oc];
#pragma unroll
        for (int k = 0; k < HID; ++k)
            a = fmaf(smean[wv][n8][k], W_l[oc * HID + k],
                     fmaf(h_f32[gn * HID + k], W_r[oc * HID + k], a));
        out[gn * OUT_CH + oc] = a;
    }
}

extern "C" void kernel_launch(void* const* d_in, const int* in_sizes, int n_in,
                              void* d_out, int out_size, void* d_ws, size_t ws_size,
                              hipStream_t stream) {
    const float* x    = (const float*)d_in[0];
    const int* eidx   = (const int*)d_in[1];
    const float* W1_l = (const float*)d_in[3];
    const float* b1   = (const float*)d_in[4];
    const float* W1_r = (const float*)d_in[5];
    const float* W2_l = (const float*)d_in[6];
    const float* b2   = (const float*)d_in[7];
    const float* W2_r = (const float*)d_in[8];
    float* out = (float*)d_out;

    const uint4* src4 = (const uint4*)eidx;
    const uint4* dst4 = (const uint4*)(eidx + N_EDGES);

    // Workspace layout (4-byte words), every region written each launch:
    //   binbuf  @ 0           (9,437,184)  1024 bin regions of 8x1152 words
    //   tail    @ 9,437,184   (8,192)      zeroed by prep
    //   xb      @ 9,445,376   (802,816)    bf16 x rows (16 ush = 8 words/row)
    //   hb      @ 10,248,192  (800,000)    bf16 h rows
    //   h_f32   @ 11,048,192  (1,600,000)
    //   rowptr  @ 12,648,192  (100,352)
    //   deg     @ 12,748,544  (100,352)    zeroed by prep, filled by binfill atomics
    // total 12,848,896 words = 51.4 MB (ws ~400 MB per fill counters)
    int*            wsi      = (int*)d_ws;
    unsigned*       binbuf   = (unsigned*)wsi;
    int*            tail     = wsi + 9437184;
    unsigned short* x_bf16   = (unsigned short*)(wsi + 9445376);
    unsigned short* h_bf16   = (unsigned short*)(wsi + 10248192);
    float*          h_f32    = (float*)(wsi + 11048192);
    int*            rowptr   = wsi + 12648192;
    int*            deg      = wsi + 12748544;

    prep_kernel<<<(NBINS * BINW * 16 + 1023) / 1024, 1024, 0, stream>>>(x, x_bf16, tail, deg);
    binfill_kernel<<<N_TILES, BF_THREADS, 0, stream>>>(src4, dst4, tail, binbuf, deg);
    sortagg1_kernel<<<NBINS, 512, 0, stream>>>((const unsigned*)x_bf16, x, binbuf, tail,
                                               rowptr, deg, W1_l, b1, W1_r, h_f32, h_bf16);
    agg2_kernel<<<3125, 256, 0, stream>>>((const unsigned*)h_bf16, h_f32, binbuf,
                                          rowptr, deg, W2_l, b2, W2_r, out);
}

// Round 2
// 301.948 us; speedup vs baseline: 1.7822x; 1.7822x over previous
//
#include <hip/hip_runtime.h>

#define N_NODES 100000
#define N_EDGES 6400000
#define IN_CH 14
#define HID 16
#define OUT_CH 8

#define NBINS 1024
#define BINW 98             // 1024*98 = 100352 >= 100000
#define NCLS 8              // XCD classes (blockIdx & 7)
#define SLABC 1152          // words per (bin,class); mean 781, sigma ~28 (13-sigma cap)
#define BINREG (NCLS * SLABC)                  // 9216 words per bin region
#define BINBUF_WORDS (NBINS * BINREG)          // 9,437,184
#define SORT_CAP 7168       // LDS staging cap per bin; mean 6250, sigma ~79
#define BF_THREADS 1024
#define BF_TILE 8192
#define BF_EPT (BF_TILE / BF_THREADS)          // 8 edges/thread
#define N_TILES ((N_EDGES + BF_TILE - 1) / BF_TILE)   // 782
#define LHN 128             // pow2 >= BINW for the per-bin scan

// round-to-nearest-even fp32 -> bf16 (as ushort)
__device__ __forceinline__ unsigned short f2bf(float f) {
    unsigned u = __float_as_uint(f);
    u += 0x7fffu + ((u >> 16) & 1u);
    return (unsigned short)(u >> 16);
}

// ---------------------------------------------------------------------------
// prep: cast x to padded bf16 rows (16 ushorts, pad=0) AND zero the 8x1024
// tail counters (workspace is 0xAA-poisoned before every launch).
// NOTE (r1 post-mortem): per-edge global atomics are ~32B HBM RMW each on
// MI355X (device-scope atomics bypass the non-coherent per-XCD L2) -> the
// deg-via-binfill-atomics experiment cost +200MB WRITE_SIZE. Reverted.
// ---------------------------------------------------------------------------
__global__ void prep_kernel(const float* __restrict__ x, unsigned short* __restrict__ xb,
                            int* __restrict__ tail) {
    int i = blockIdx.x * blockDim.x + threadIdx.x;
    if (i < NCLS * NBINS) tail[i] = 0;
    if (i >= (NBINS * BINW) * 16) return;
    int n = i >> 4, c = i & 15;
    float v = (n < N_NODES && c < IN_CH) ? x[n * IN_CH + c] : 0.0f;
    xb[i] = f2bf(v);
}

// ---------------------------------------------------------------------------
// binfill: per 8192-edge tile, LDS counting-sort by bin, reserve a dense
// chunk in the bin's CLASS sub-slab (class = blockIdx&7 ~ XCD) via one tail
// atomic, then LINEAR write-out. Same-class tiles write adjacent chunks ->
// each 64B line is produced by ~one XCD -> minimal write amplification.
// Packed word: src [0,17) | local dst [17,24).
// ---------------------------------------------------------------------------
__global__ __launch_bounds__(BF_THREADS)
void binfill_kernel(const uint4* __restrict__ src4, const uint4* __restrict__ dst4,
                    int* __restrict__ tail, unsigned* __restrict__ binbuf) {
    __shared__ unsigned stile[BF_TILE];        // 32 KB sorted packed words
    __shared__ unsigned short stbin[BF_TILE];  // 16 KB bin id per sorted slot
    __shared__ int lh[NBINS];                  // 4 KB tile histogram
    __shared__ int lx[NBINS];                  // 4 KB exclusive offsets
    __shared__ int lofs[NBINS];                // 4 KB reserved sub-slab offsets
    __shared__ int wsum[16];

    const int t = threadIdx.x;
    const int lane = t & 63;
    const int wv = t >> 6;                     // 16 waves
    const int cls = blockIdx.x & (NCLS - 1);
    const long long tb = (long long)blockIdx.x * BF_TILE;

    lh[t] = 0;                                 // BF_THREADS == NBINS
    __syncthreads();

    unsigned epack[BF_EPT];
    int      ebin[BF_EPT];
    int      erank[BF_EPT];

#pragma unroll
    for (int sw = 0; sw < BF_EPT / 4; ++sw) {
        long long u = tb / 4 + (long long)sw * BF_THREADS + t;
        int k = sw * 4;
        if (u * 4 < N_EDGES) {
            uint4 s = src4[u];
            uint4 d = dst4[u];
            unsigned b;
            b = d.x / BINW; epack[k+0] = s.x | ((d.x - b*BINW) << 17); ebin[k+0] = (int)b; erank[k+0] = atomicAdd(&lh[b], 1);
            b = d.y / BINW; epack[k+1] = s.y | ((d.y - b*BINW) << 17); ebin[k+1] = (int)b; erank[k+1] = atomicAdd(&lh[b], 1);
            b = d.z / BINW; epack[k+2] = s.z | ((d.z - b*BINW) << 17); ebin[k+2] = (int)b; erank[k+2] = atomicAdd(&lh[b], 1);
            b = d.w / BINW; epack[k+3] = s.w | ((d.w - b*BINW) << 17); ebin[k+3] = (int)b; erank[k+3] = atomicAdd(&lh[b], 1);
        } else {
            ebin[k+0] = ebin[k+1] = ebin[k+2] = ebin[k+3] = -1;
        }
    }
    __syncthreads();

    // wave-level exclusive scan of lh (1024 entries, 16 waves)
    int v = lh[t];
    int incl = v;
#pragma unroll
    for (int d = 1; d < 64; d <<= 1) {
        int o = __shfl_up(incl, d, 64);
        if (lane >= d) incl += o;
    }
    if (lane == 63) wsum[wv] = incl;
    __syncthreads();
    if (t < 16) {
        int s = wsum[t];
        int si = s;
#pragma unroll
        for (int d = 1; d < 16; d <<= 1) {
            int o = __shfl_up(si, d, 16);
            if (t >= d) si += o;
        }
        wsum[t] = si - s;                      // exclusive wave offset
    }
    __syncthreads();
    lx[t] = incl - v + wsum[wv];               // exclusive within tile
    lofs[t] = atomicAdd(&tail[cls * NBINS + t], v);   // offset within sub-slab
    __syncthreads();

    // place into LDS sorted-by-bin order
#pragma unroll
    for (int k = 0; k < BF_EPT; ++k) {
        if (ebin[k] >= 0) {
            int pos = lx[ebin[k]] + erank[k];
            stile[pos] = epack[k];
            stbin[pos] = (unsigned short)ebin[k];
        }
    }
    __syncthreads();

    // linear coalesced write-out into per-(bin,class) sub-slabs
    int cnt = (int)((N_EDGES - tb < BF_TILE) ? (N_EDGES - tb) : BF_TILE);
    for (int i = t; i < cnt; i += BF_THREADS) {
        int b = stbin[i];
        int slot = lofs[b] + (i - lx[b]);
        if ((unsigned)slot < (unsigned)SLABC)  // deterministic: never overflows
            binbuf[b * BINREG + cls * SLABC + slot] = stile[i];
    }
}

// ---------------------------------------------------------------------------
// FUSED bin-local counting sort + layer-1 aggregation. One block per bin:
// 1024 blocks, 512 threads, ~30 KB LDS.
// P0 segment bookkeeping (parallel tail loads) ; P1 uint4-vectorized hist ;
// P2 wave-scan + rowptr/deg ; P3 uint4-vectorized rank -> sorted src in LDS ;
// P4 coalesced csr write ; P5 gather with 4-lane/uint2 groups (one pass) ;
// P6 fused MLP epilogue.
// ---------------------------------------------------------------------------
__global__ __launch_bounds__(512)
void sortagg1_kernel(const unsigned* __restrict__ xb, const float* __restrict__ x,
                     unsigned* __restrict__ binbuf, const int* __restrict__ tail,
                     int* __restrict__ rowptr, int* __restrict__ deg,
                     const float* __restrict__ W_l, const float* __restrict__ bias,
                     const float* __restrict__ W_r,
                     float* __restrict__ h_f32, unsigned short* __restrict__ h_bf16) {
    __shared__ __attribute__((aligned(16))) unsigned sbuf[SORT_CAP]; // 28,672 B; overlaid by smean in P6
    __shared__ int lhist[LHN];
    __shared__ int loff[LHN];
    __shared__ int lcur[LHN];
    __shared__ int wtot[2];
    __shared__ int segcnt[NCLS];
    __shared__ int totc[1];

    const int b = blockIdx.x;
    const int t = threadIdx.x;
    const int regbase = b * BINREG;

    // P0a: per-class segment counts loaded in parallel (8 lanes of wave 0)
    if (t < NCLS) {
        int c = tail[t * NBINS + b];
        if (c < 0) c = 0;
        if (c > SLABC) c = SLABC;
        segcnt[t] = c;
    }
    if (t < LHN) lhist[t] = 0;
    // P0b: LDS-only serial cap-check; same wave as the segcnt writes, so
    // program order + compiler lgkmcnt gives the ordering without a barrier.
    if (t == 0) {
        int s = 0;
        for (int k = 0; k < NCLS; ++k) {
            int c = segcnt[k];
            if (s + c > SORT_CAP) { c = SORT_CAP - s; segcnt[k] = c; }  // insurance
            s += c;
        }
        totc[0] = s;
    }
    __syncthreads();
    const int cnt = totc[0];

    // P1: local-node histogram over the 8 segments, uint4-vectorized
    for (int k = 0; k < NCLS; ++k) {
        const int base = regbase + k * SLABC;
        const int c = segcnt[k];
        const uint4* b4 = (const uint4*)(binbuf + base);   // 16B-aligned by construction
        const int nv = c >> 2;
        for (int i = t; i < nv; i += 512) {
            uint4 w = b4[i];
            atomicAdd(&lhist[w.x >> 17], 1);
            atomicAdd(&lhist[w.y >> 17], 1);
            atomicAdd(&lhist[w.z >> 17], 1);
            atomicAdd(&lhist[w.w >> 17], 1);
        }
        int r = (nv << 2) + t;
        if (r < c) atomicAdd(&lhist[binbuf[base + r] >> 17], 1);
    }
    __syncthreads();

    // P2: wave-level exclusive scan of 128 entries
    int v = (t < LHN) ? lhist[t] : 0;
    int incl = v;
#pragma unroll
    for (int d = 1; d < 64; d <<= 1) {
        int o = __shfl_up(incl, d, 64);
        if ((t & 63) >= d) incl += o;
    }
    if (t < LHN && (t & 63) == 63) wtot[t >> 6] = incl;
    __syncthreads();
    if (t < LHN) {
        int excl = incl - v + ((t >= 64) ? wtot[0] : 0);
        loff[t] = excl;
        lcur[t] = excl;
        if (t < BINW) {
            int gn = b * BINW + t;
            if (gn < N_NODES) { rowptr[gn] = regbase + excl; deg[gn] = v; }
        }
    }
    __syncthreads();

    // P3: rank & place sorted src into LDS, uint4-vectorized re-read (L2-hot)
    for (int k = 0; k < NCLS; ++k) {
        const int base = regbase + k * SLABC;
        const int c = segcnt[k];
        const uint4* b4 = (const uint4*)(binbuf + base);
        const int nv = c >> 2;
        for (int i = t; i < nv; i += 512) {
            uint4 w = b4[i];
            int p0 = atomicAdd(&lcur[w.x >> 17], 1);
            int p1 = atomicAdd(&lcur[w.y >> 17], 1);
            int p2 = atomicAdd(&lcur[w.z >> 17], 1);
            int p3 = atomicAdd(&lcur[w.w >> 17], 1);
            if (p0 < cnt) sbuf[p0] = w.x & 0x1FFFFu;
            if (p1 < cnt) sbuf[p1] = w.y & 0x1FFFFu;
            if (p2 < cnt) sbuf[p2] = w.z & 0x1FFFFu;
            if (p3 < cnt) sbuf[p3] = w.w & 0x1FFFFu;
        }
        int r = (nv << 2) + t;
        if (r < c) {
            unsigned w = binbuf[base + r];
            int pos = atomicAdd(&lcur[w >> 17], 1);
            if (pos < cnt) sbuf[pos] = w & 0x1FFFFu;
        }
    }
    __syncthreads();

    // P4: coalesced copy-out of sorted csr (contiguous from region start)
    for (int i = t; i < cnt; i += 512)
        binbuf[regbase + i] = sbuf[i];

    // P5: gather. 128 groups of 4 lanes; lane l holds channels 4l..4l+3
    // (uint2 = 8B per load; half the gather instructions of the 8-lane form).
    const int g = t >> 2;
    const int l = t & 3;
    const uint2* xb2 = (const uint2*)xb;       // row = 4 uint2
    float m0 = 0.0f, m1 = 0.0f, m2 = 0.0f, m3 = 0.0f;
    if (g < BINW) {
        int dg = lhist[g];
        int off = loff[g];
        float a0 = 0.0f, a1 = 0.0f, a2 = 0.0f, a3 = 0.0f;
        int i = 0;
        for (; i + 4 <= dg; i += 4) {
            unsigned s0 = sbuf[off + i], s1 = sbuf[off + i + 1];
            unsigned s2 = sbuf[off + i + 2], s3 = sbuf[off + i + 3];
            uint2 u0 = xb2[s0 * 4 + l];
            uint2 u1 = xb2[s1 * 4 + l];
            uint2 u2 = xb2[s2 * 4 + l];
            uint2 u3 = xb2[s3 * 4 + l];
            a0 += __uint_as_float(u0.x << 16);  a1 += __uint_as_float(u0.x & 0xffff0000u);
            a2 += __uint_as_float(u0.y << 16);  a3 += __uint_as_float(u0.y & 0xffff0000u);
            a0 += __uint_as_float(u1.x << 16);  a1 += __uint_as_float(u1.x & 0xffff0000u);
            a2 += __uint_as_float(u1.y << 16);  a3 += __uint_as_float(u1.y & 0xffff0000u);
            a0 += __uint_as_float(u2.x << 16);  a1 += __uint_as_float(u2.x & 0xffff0000u);
            a2 += __uint_as_float(u2.y << 16);  a3 += __uint_as_float(u2.y & 0xffff0000u);
            a0 += __uint_as_float(u3.x << 16);  a1 += __uint_as_float(u3.x & 0xffff0000u);
            a2 += __uint_as_float(u3.y << 16);  a3 += __uint_as_float(u3.y & 0xffff0000u);
        }
        for (; i < dg; ++i) {
            uint2 u0 = xb2[sbuf[off + i] * 4 + l];
            a0 += __uint_as_float(u0.x << 16);  a1 += __uint_as_float(u0.x & 0xffff0000u);
            a2 += __uint_as_float(u0.y << 16);  a3 += __uint_as_float(u0.y & 0xffff0000u);
        }
        float inv = 1.0f / fmaxf((float)dg, 1.0f);
        m0 = a0 * inv; m1 = a1 * inv; m2 = a2 * inv; m3 = a3 * inv;
    }
    __syncthreads();                 // all sbuf reads done -> safe to overlay

    // P6: overlay means (float4 store), fused MLP epilogue
    float* smean = (float*)sbuf;     // 98*16 floats = 6,272 B < SORT_CAP*4
    if (g < BINW) {
        float4 mv; mv.x = m0; mv.y = m1; mv.z = m2; mv.w = m3;
        *((float4*)(smean + g * 16 + 4 * l)) = mv;   // 16B-aligned
    }
    __syncthreads();

    const int nodeBase = b * BINW;
    for (int i = t; i < BINW * HID; i += 512) {
        int n = i >> 4, oc = i & 15;
        int gn = nodeBase + n;
        if (gn >= N_NODES) break;
        float a = bias[oc];
#pragma unroll
        for (int k = 0; k < IN_CH; ++k)
            a = fmaf(smean[n * 16 + k], W_l[oc * IN_CH + k],
                     fmaf(x[gn * IN_CH + k], W_r[oc * IN_CH + k], a));
        float vv = fmaxf(a, 0.0f);
        h_f32[gn * HID + oc] = vv;
        h_bf16[gn * HID + oc] = f2bf(vv);
    }
}

// ---------------------------------------------------------------------------
// Layer 2 aggregation: no atomics, register accumulation, 4 lanes/node with
// uint2 (8B) gathers over sorted csr -> half the load instructions, 2x node
// parallelism per wave (16 nodes/wave, 64 nodes/block). 8x unroll.
// ---------------------------------------------------------------------------
__global__ __launch_bounds__(256)
void agg2_kernel(const unsigned* __restrict__ hb,
                 const float* __restrict__ h_f32,
                 const unsigned* __restrict__ csr,
                 const int* __restrict__ rowptr, const int* __restrict__ deg,
                 const float* __restrict__ W_l, const float* __restrict__ bias,
                 const float* __restrict__ W_r, float* __restrict__ out) {
    __shared__ __attribute__((aligned(16))) float smean[4][16][16];  // 4 KB

    const int t = threadIdx.x;
    const int wv = t >> 6;
    const int lane = t & 63;
    const int g = lane >> 2;                   // 16 nodes per wave
    const int l = lane & 3;                    // lane l holds ch 4l..4l+3
    const int node = (blockIdx.x * 4 + wv) * 16 + g;

    int beg = 0, d = 0;
    if (node < N_NODES) {
        beg = rowptr[node];
        d = deg[node];
        if (beg < 0) beg = 0;
        if (d < 0) d = 0;
        if (beg + d > BINBUF_WORDS) d = BINBUF_WORDS - beg;
    }

    const uint2* hb2 = (const uint2*)hb;       // row = 4 uint2
    float a0 = 0.0f, a1 = 0.0f, a2 = 0.0f, a3 = 0.0f;
    int i = 0;
    for (; i + 8 <= d; i += 8) {
        unsigned s0 = csr[beg + i]     & 0x1FFFFu;
        unsigned s1 = csr[beg + i + 1] & 0x1FFFFu;
        unsigned s2 = csr[beg + i + 2] & 0x1FFFFu;
        unsigned s3 = csr[beg + i + 3] & 0x1FFFFu;
        unsigned s4 = csr[beg + i + 4] & 0x1FFFFu;
        unsigned s5 = csr[beg + i + 5] & 0x1FFFFu;
        unsigned s6 = csr[beg + i + 6] & 0x1FFFFu;
        unsigned s7 = csr[beg + i + 7] & 0x1FFFFu;
        uint2 u0 = hb2[s0 * 4 + l];
        uint2 u1 = hb2[s1 * 4 + l];
        uint2 u2 = hb2[s2 * 4 + l];
        uint2 u3 = hb2[s3 * 4 + l];
        uint2 u4 = hb2[s4 * 4 + l];
        uint2 u5 = hb2[s5 * 4 + l];
        uint2 u6 = hb2[s6 * 4 + l];
        uint2 u7 = hb2[s7 * 4 + l];
        a0 += __uint_as_float(u0.x << 16);  a1 += __uint_as_float(u0.x & 0xffff0000u);
        a2 += __uint_as_float(u0.y << 16);  a3 += __uint_as_float(u0.y & 0xffff0000u);
        a0 += __uint_as_float(u1.x << 16);  a1 += __uint_as_float(u1.x & 0xffff0000u);
        a2 += __uint_as_float(u1.y << 16);  a3 += __uint_as_float(u1.y & 0xffff0000u);
        a0 += __uint_as_float(u2.x << 16);  a1 += __uint_as_float(u2.x & 0xffff0000u);
        a2 += __uint_as_float(u2.y << 16);  a3 += __uint_as_float(u2.y & 0xffff0000u);
        a0 += __uint_as_float(u3.x << 16);  a1 += __uint_as_float(u3.x & 0xffff0000u);
        a2 += __uint_as_float(u3.y << 16);  a3 += __uint_as_float(u3.y & 0xffff0000u);
        a0 += __uint_as_float(u4.x << 16);  a1 += __uint_as_float(u4.x & 0xffff0000u);
        a2 += __uint_as_float(u4.y << 16);  a3 += __uint_as_float(u4.y & 0xffff0000u);
        a0 += __uint_as_float(u5.x << 16);  a1 += __uint_as_float(u5.x & 0xffff0000u);
        a2 += __uint_as_float(u5.y << 16);  a3 += __uint_as_float(u5.y & 0xffff0000u);
        a0 += __uint_as_float(u6.x << 16);  a1 += __uint_as_float(u6.x & 0xffff0000u);
        a2 += __uint_as_float(u6.y << 16);  a3 += __uint_as_float(u6.y & 0xffff0000u);
        a0 += __uint_as_float(u7.x << 16);  a1 += __uint_as_float(u7.x & 0xffff0000u);
        a2 += __uint_as_float(u7.y << 16);  a3 += __uint_as_float(u7.y & 0xffff0000u);
    }
    for (; i < d; ++i) {
        unsigned s0 = csr[beg + i] & 0x1FFFFu;
        uint2 u0 = hb2[s0 * 4 + l];
        a0 += __uint_as_float(u0.x << 16);  a1 += __uint_as_float(u0.x & 0xffff0000u);
        a2 += __uint_as_float(u0.y << 16);  a3 += __uint_as_float(u0.y & 0xffff0000u);
    }
    float inv = 1.0f / fmaxf((float)d, 1.0f);
    {
        float4 mv; mv.x = a0 * inv; mv.y = a1 * inv; mv.z = a2 * inv; mv.w = a3 * inv;
        *((float4*)(&smean[wv][g][4 * l])) = mv;   // 16B-aligned
    }
    // wave-internal LDS ordering (write then read in program order) — same
    // wave covers all 16 nodes of smean[wv], so no block barrier needed.

    // epilogue: 16 nodes x 8 oc = 128 tasks per wave -> 2 iterations
#pragma unroll
    for (int it = 0; it < 2; ++it) {
        int n8 = (lane >> 3) + 8 * it;         // 0..15
        int oc = lane & 7;
        int gn = (blockIdx.x * 4 + wv) * 16 + n8;
        if (gn < N_NODES) {
            float a = bias[oc];
#pragma unroll
            for (int k = 0; k < HID; ++k)
                a = fmaf(smean[wv][n8][k], W_l[oc * HID + k],
                         fmaf(h_f32[gn * HID + k], W_r[oc * HID + k], a));
            out[gn * OUT_CH + oc] = a;
        }
    }
}

extern "C" void kernel_launch(void* const* d_in, const int* in_sizes, int n_in,
                              void* d_out, int out_size, void* d_ws, size_t ws_size,
                              hipStream_t stream) {
    const float* x    = (const float*)d_in[0];
    const int* eidx   = (const int*)d_in[1];
    const float* W1_l = (const float*)d_in[3];
    const float* b1   = (const float*)d_in[4];
    const float* W1_r = (const float*)d_in[5];
    const float* W2_l = (const float*)d_in[6];
    const float* b2   = (const float*)d_in[7];
    const float* W2_r = (const float*)d_in[8];
    float* out = (float*)d_out;

    const uint4* src4 = (const uint4*)eidx;
    const uint4* dst4 = (const uint4*)(eidx + N_EDGES);

    // Workspace layout (4-byte words), every region written each launch:
    //   binbuf  @ 0           (9,437,184)  1024 bin regions of 8x1152 words
    //   tail    @ 9,437,184   (8,192)      zeroed by prep
    //   xb      @ 9,445,376   (802,816)    bf16 x rows (16 ush = 8 words/row)
    //   hb      @ 10,248,192  (800,000)    bf16 h rows
    //   h_f32   @ 11,048,192  (1,600,000)
    //   rowptr  @ 12,648,192  (100,352)
    //   deg     @ 12,748,544  (100,352)
    // total 12,848,896 words = 51.4 MB (ws ~400 MB per fill counters)
    int*            wsi      = (int*)d_ws;
    unsigned*       binbuf   = (unsigned*)wsi;
    int*            tail     = wsi + 9437184;
    unsigned short* x_bf16   = (unsigned short*)(wsi + 9445376);
    unsigned short* h_bf16   = (unsigned short*)(wsi + 10248192);
    float*          h_f32    = (float*)(wsi + 11048192);
    int*            rowptr   = wsi + 12648192;
    int*            deg      = wsi + 12748544;

    prep_kernel<<<(NBINS * BINW * 16 + 1023) / 1024, 1024, 0, stream>>>(x, x_bf16, tail);
    binfill_kernel<<<N_TILES, BF_THREADS, 0, stream>>>(src4, dst4, tail, binbuf);
    sortagg1_kernel<<<NBINS, 512, 0, stream>>>((const unsigned*)x_bf16, x, binbuf, tail,
                                               rowptr, deg, W1_l, b1, W1_r, h_f32, h_bf16);
    // 64 nodes per block -> 1563 blocks covers 100,032 (tail nodes guarded)
    agg2_kernel<<<(N_NODES + 63) / 64, 256, 0, stream>>>((const unsigned*)h_bf16, h_f32, binbuf,
                                          rowptr, deg, W2_l, b2, W2_r, out);
}

// Round 3
// 298.529 us; speedup vs baseline: 1.8026x; 1.0115x over previous
//
#include <hip/hip_runtime.h>

#define N_NODES 100000
#define N_EDGES 6400000
#define IN_CH 14
#define HID 16
#define OUT_CH 8

#define NBINS 1024
#define BINW 98             // 1024*98 = 100352 >= 100000
#define NCLS 8              // XCD classes (blockIdx & 7)
#define SLABC 1152          // words per (bin,class); mean 781, sigma ~28 (13-sigma cap)
#define BINREG (NCLS * SLABC)                  // 9216 words per bin region
#define BINBUF_WORDS (NBINS * BINREG)          // 9,437,184
#define SORT_CAP 7168       // LDS staging cap per bin; mean 6250, sigma ~79
#define BF_THREADS 1024
#define BF_TILE 8192
#define BF_EPT (BF_TILE / BF_THREADS)          // 8 edges/thread
#define N_TILES ((N_EDGES + BF_TILE - 1) / BF_TILE)   // 782
#define LHN 128             // pow2 >= BINW for the per-bin scan

// round-to-nearest-even fp32 -> bf16 (as ushort)
__device__ __forceinline__ unsigned short f2bf(float f) {
    unsigned u = __float_as_uint(f);
    u += 0x7fffu + ((u >> 16) & 1u);
    return (unsigned short)(u >> 16);
}

// ---------------------------------------------------------------------------
// prep: cast x to padded bf16 rows (16 ushorts, pad=0) AND zero the 8x1024
// tail counters (workspace is 0xAA-poisoned before every launch).
// NOTE (r1): per-edge device atomics = ~32B HBM RMW each on MI355X. Never.
// ---------------------------------------------------------------------------
__global__ void prep_kernel(const float* __restrict__ x, unsigned short* __restrict__ xb,
                            int* __restrict__ tail) {
    int i = blockIdx.x * blockDim.x + threadIdx.x;
    if (i < NCLS * NBINS) tail[i] = 0;
    if (i >= (NBINS * BINW) * 16) return;
    int n = i >> 4, c = i & 15;
    float v = (n < N_NODES && c < IN_CH) ? x[n * IN_CH + c] : 0.0f;
    xb[i] = f2bf(v);
}

// ---------------------------------------------------------------------------
// binfill: per 8192-edge tile, LDS counting-sort by bin, reserve a dense
// chunk in the bin's CLASS sub-slab (class = blockIdx&7 ~ XCD) via one tail
// atomic, then LINEAR write-out. Packed word: src [0,17) | local dst [17,24).
// ---------------------------------------------------------------------------
__global__ __launch_bounds__(BF_THREADS)
void binfill_kernel(const uint4* __restrict__ src4, const uint4* __restrict__ dst4,
                    int* __restrict__ tail, unsigned* __restrict__ binbuf) {
    __shared__ unsigned stile[BF_TILE];        // 32 KB sorted packed words
    __shared__ unsigned short stbin[BF_TILE];  // 16 KB bin id per sorted slot
    __shared__ int lh[NBINS];                  // 4 KB tile histogram
    __shared__ int lx[NBINS];                  // 4 KB exclusive offsets
    __shared__ int lofs[NBINS];                // 4 KB reserved sub-slab offsets
    __shared__ int wsum[16];

    const int t = threadIdx.x;
    const int lane = t & 63;
    const int wv = t >> 6;                     // 16 waves
    const int cls = blockIdx.x & (NCLS - 1);
    const long long tb = (long long)blockIdx.x * BF_TILE;

    lh[t] = 0;                                 // BF_THREADS == NBINS
    __syncthreads();

    unsigned epack[BF_EPT];
    int      ebin[BF_EPT];
    int      erank[BF_EPT];

#pragma unroll
    for (int sw = 0; sw < BF_EPT / 4; ++sw) {
        long long u = tb / 4 + (long long)sw * BF_THREADS + t;
        int k = sw * 4;
        if (u * 4 < N_EDGES) {
            uint4 s = src4[u];
            uint4 d = dst4[u];
            unsigned b;
            b = d.x / BINW; epack[k+0] = s.x | ((d.x - b*BINW) << 17); ebin[k+0] = (int)b; erank[k+0] = atomicAdd(&lh[b], 1);
            b = d.y / BINW; epack[k+1] = s.y | ((d.y - b*BINW) << 17); ebin[k+1] = (int)b; erank[k+1] = atomicAdd(&lh[b], 1);
            b = d.z / BINW; epack[k+2] = s.z | ((d.z - b*BINW) << 17); ebin[k+2] = (int)b; erank[k+2] = atomicAdd(&lh[b], 1);
            b = d.w / BINW; epack[k+3] = s.w | ((d.w - b*BINW) << 17); ebin[k+3] = (int)b; erank[k+3] = atomicAdd(&lh[b], 1);
        } else {
            ebin[k+0] = ebin[k+1] = ebin[k+2] = ebin[k+3] = -1;
        }
    }
    __syncthreads();

    // wave-level exclusive scan of lh (1024 entries, 16 waves)
    int v = lh[t];
    int incl = v;
#pragma unroll
    for (int d = 1; d < 64; d <<= 1) {
        int o = __shfl_up(incl, d, 64);
        if (lane >= d) incl += o;
    }
    if (lane == 63) wsum[wv] = incl;
    __syncthreads();
    if (t < 16) {
        int s = wsum[t];
        int si = s;
#pragma unroll
        for (int d = 1; d < 16; d <<= 1) {
            int o = __shfl_up(si, d, 16);
            if (t >= d) si += o;
        }
        wsum[t] = si - s;                      // exclusive wave offset
    }
    __syncthreads();
    lx[t] = incl - v + wsum[wv];               // exclusive within tile
    lofs[t] = atomicAdd(&tail[cls * NBINS + t], v);   // offset within sub-slab
    __syncthreads();

    // place into LDS sorted-by-bin order
#pragma unroll
    for (int k = 0; k < BF_EPT; ++k) {
        if (ebin[k] >= 0) {
            int pos = lx[ebin[k]] + erank[k];
            stile[pos] = epack[k];
            stbin[pos] = (unsigned short)ebin[k];
        }
    }
    __syncthreads();

    // linear coalesced write-out into per-(bin,class) sub-slabs
    int cnt = (int)((N_EDGES - tb < BF_TILE) ? (N_EDGES - tb) : BF_TILE);
    for (int i = t; i < cnt; i += BF_THREADS) {
        int b = stbin[i];
        int slot = lofs[b] + (i - lx[b]);
        if ((unsigned)slot < (unsigned)SLABC)  // deterministic: never overflows
            binbuf[b * BINREG + cls * SLABC + slot] = stile[i];
    }
}

// ---------------------------------------------------------------------------
// FUSED bin-local counting sort + layer-1 aggregation. One block per bin:
// 1024 blocks, 512 threads.
// r3 redesign: the 8 class segments are loaded ONCE into registers (8 x uint4
// per thread, issued back-to-back -> 8 loads in flight instead of 8 serialized
// latency chains), then BOTH the histogram (P1) and the rank/scatter (P3) run
// from registers. The 25.6 MB P3 re-read of binbuf is gone.
// ---------------------------------------------------------------------------
__global__ __launch_bounds__(512, 4)
void sortagg1_kernel(const unsigned* __restrict__ xb, const float* __restrict__ x,
                     unsigned* __restrict__ binbuf, const int* __restrict__ tail,
                     int* __restrict__ rowptr, int* __restrict__ deg,
                     const float* __restrict__ W_l, const float* __restrict__ bias,
                     const float* __restrict__ W_r,
                     float* __restrict__ h_f32, unsigned short* __restrict__ h_bf16) {
    __shared__ __attribute__((aligned(16))) unsigned sbuf[SORT_CAP]; // 28,672 B; overlaid by smean in P6
    __shared__ int lhist[LHN];
    __shared__ int loff[LHN];
    __shared__ int lcur[LHN];
    __shared__ int wtot[2];
    __shared__ int segcnt[NCLS];
    __shared__ int totc[1];

    const int b = blockIdx.x;
    const int t = threadIdx.x;
    const int regbase = b * BINREG;

    // P0a: per-class segment counts loaded in parallel (8 lanes of wave 0)
    if (t < NCLS) {
        int c = tail[t * NBINS + b];
        if (c < 0) c = 0;
        if (c > SLABC) c = SLABC;
        segcnt[t] = c;
    }
    if (t < LHN) lhist[t] = 0;
    // P0b: LDS-only serial cap-check; same wave as the segcnt writes (program
    // order within the wave gives the ordering without a barrier).
    if (t == 0) {
        int s = 0;
        for (int k = 0; k < NCLS; ++k) {
            int c = segcnt[k];
            if (s + c > SORT_CAP) { c = SORT_CAP - s; segcnt[k] = c; }  // insurance
            s += c;
        }
        totc[0] = s;
    }
    __syncthreads();
    const int cnt = totc[0];

    // --- load all 8 class segments into registers; one uint4 per class per
    // thread. nv = ceil(c/4) <= 288 < 512 so one vector covers a segment.
    // SLABC % 4 == 0 -> the full uint4 load is always inside the slab.
    uint4 seg[NCLS];
    int   segc[NCLS];
#pragma unroll
    for (int k = 0; k < NCLS; ++k) {
        segc[k] = segcnt[k];
        if ((t << 2) < segc[k])
            seg[k] = *((const uint4*)(binbuf + regbase + k * SLABC) + t);
    }

    // P1: local-node histogram from registers
#pragma unroll
    for (int k = 0; k < NCLS; ++k) {
        const int c = segc[k], w0 = t << 2;
        if (w0 < c) {
            atomicAdd(&lhist[seg[k].x >> 17], 1);
            if (w0 + 1 < c) atomicAdd(&lhist[seg[k].y >> 17], 1);
            if (w0 + 2 < c) atomicAdd(&lhist[seg[k].z >> 17], 1);
            if (w0 + 3 < c) atomicAdd(&lhist[seg[k].w >> 17], 1);
        }
    }
    __syncthreads();

    // P2: wave-level exclusive scan of 128 entries
    int v = (t < LHN) ? lhist[t] : 0;
    int incl = v;
#pragma unroll
    for (int d = 1; d < 64; d <<= 1) {
        int o = __shfl_up(incl, d, 64);
        if ((t & 63) >= d) incl += o;
    }
    if (t < LHN && (t & 63) == 63) wtot[t >> 6] = incl;
    __syncthreads();
    if (t < LHN) {
        int excl = incl - v + ((t >= 64) ? wtot[0] : 0);
        loff[t] = excl;
        lcur[t] = excl;
        if (t < BINW) {
            int gn = b * BINW + t;
            if (gn < N_NODES) { rowptr[gn] = regbase + excl; deg[gn] = v; }
        }
    }
    __syncthreads();

    // P3: rank & scatter into sorted LDS order, straight from registers
#pragma unroll
    for (int k = 0; k < NCLS; ++k) {
        const int c = segc[k], w0 = t << 2;
        if (w0 < c) {
            int p0 = atomicAdd(&lcur[seg[k].x >> 17], 1);
            if (p0 < cnt) sbuf[p0] = seg[k].x & 0x1FFFFu;
            if (w0 + 1 < c) {
                int p1 = atomicAdd(&lcur[seg[k].y >> 17], 1);
                if (p1 < cnt) sbuf[p1] = seg[k].y & 0x1FFFFu;
            }
            if (w0 + 2 < c) {
                int p2 = atomicAdd(&lcur[seg[k].z >> 17], 1);
                if (p2 < cnt) sbuf[p2] = seg[k].z & 0x1FFFFu;
            }
            if (w0 + 3 < c) {
                int p3 = atomicAdd(&lcur[seg[k].w >> 17], 1);
                if (p3 < cnt) sbuf[p3] = seg[k].w & 0x1FFFFu;
            }
        }
    }
    __syncthreads();

    // P4: coalesced copy-out of sorted csr (contiguous from region start)
    for (int i = t; i < cnt; i += 512)
        binbuf[regbase + i] = sbuf[i];

    // P5: gather. 128 groups of 4 lanes; lane l holds channels 4l..4l+3.
    const int g = t >> 2;
    const int l = t & 3;
    const uint2* xb2 = (const uint2*)xb;       // row = 4 uint2
    float m0 = 0.0f, m1 = 0.0f, m2 = 0.0f, m3 = 0.0f;
    if (g < BINW) {
        int dg = lhist[g];
        int off = loff[g];
        float a0 = 0.0f, a1 = 0.0f, a2 = 0.0f, a3 = 0.0f;
        int i = 0;
        for (; i + 4 <= dg; i += 4) {
            unsigned s0 = sbuf[off + i], s1 = sbuf[off + i + 1];
            unsigned s2 = sbuf[off + i + 2], s3 = sbuf[off + i + 3];
            uint2 u0 = xb2[s0 * 4 + l];
            uint2 u1 = xb2[s1 * 4 + l];
            uint2 u2 = xb2[s2 * 4 + l];
            uint2 u3 = xb2[s3 * 4 + l];
            a0 += __uint_as_float(u0.x << 16);  a1 += __uint_as_float(u0.x & 0xffff0000u);
            a2 += __uint_as_float(u0.y << 16);  a3 += __uint_as_float(u0.y & 0xffff0000u);
            a0 += __uint_as_float(u1.x << 16);  a1 += __uint_as_float(u1.x & 0xffff0000u);
            a2 += __uint_as_float(u1.y << 16);  a3 += __uint_as_float(u1.y & 0xffff0000u);
            a0 += __uint_as_float(u2.x << 16);  a1 += __uint_as_float(u2.x & 0xffff0000u);
            a2 += __uint_as_float(u2.y << 16);  a3 += __uint_as_float(u2.y & 0xffff0000u);
            a0 += __uint_as_float(u3.x << 16);  a1 += __uint_as_float(u3.x & 0xffff0000u);
            a2 += __uint_as_float(u3.y << 16);  a3 += __uint_as_float(u3.y & 0xffff0000u);
        }
        for (; i < dg; ++i) {
            uint2 u0 = xb2[sbuf[off + i] * 4 + l];
            a0 += __uint_as_float(u0.x << 16);  a1 += __uint_as_float(u0.x & 0xffff0000u);
            a2 += __uint_as_float(u0.y << 16);  a3 += __uint_as_float(u0.y & 0xffff0000u);
        }
        float inv = 1.0f / fmaxf((float)dg, 1.0f);
        m0 = a0 * inv; m1 = a1 * inv; m2 = a2 * inv; m3 = a3 * inv;
    }
    __syncthreads();                 // all sbuf reads done -> safe to overlay

    // P6: overlay means (float4 store), fused MLP epilogue
    float* smean = (float*)sbuf;     // 98*16 floats = 6,272 B < SORT_CAP*4
    if (g < BINW) {
        float4 mv; mv.x = m0; mv.y = m1; mv.z = m2; mv.w = m3;
        *((float4*)(smean + g * 16 + 4 * l)) = mv;   // 16B-aligned
    }
    __syncthreads();

    const int nodeBase = b * BINW;
    for (int i = t; i < BINW * HID; i += 512) {
        int n = i >> 4, oc = i & 15;
        int gn = nodeBase + n;
        if (gn >= N_NODES) break;
        float a = bias[oc];
#pragma unroll
        for (int k = 0; k < IN_CH; ++k)
            a = fmaf(smean[n * 16 + k], W_l[oc * IN_CH + k],
                     fmaf(x[gn * IN_CH + k], W_r[oc * IN_CH + k], a));
        float vv = fmaxf(a, 0.0f);
        h_f32[gn * HID + oc] = vv;
        h_bf16[gn * HID + oc] = f2bf(vv);
    }
}

// ---------------------------------------------------------------------------
// Layer 2 aggregation: 4 lanes/node, uint2 gathers over sorted csr.
// r3: software-pipelined — the NEXT 8 neighbor indices are loaded after the
// current 8 gathers are issued but before they are consumed, so the
// csr->gather dependent chain no longer heads every iteration.
// ---------------------------------------------------------------------------
__global__ __launch_bounds__(256, 4)
void agg2_kernel(const unsigned* __restrict__ hb,
                 const float* __restrict__ h_f32,
                 const unsigned* __restrict__ csr,
                 const int* __restrict__ rowptr, const int* __restrict__ deg,
                 const float* __restrict__ W_l, const float* __restrict__ bias,
                 const float* __restrict__ W_r, float* __restrict__ out) {
    __shared__ __attribute__((aligned(16))) float smean[4][16][16];  // 4 KB

    const int t = threadIdx.x;
    const int wv = t >> 6;
    const int lane = t & 63;
    const int g = lane >> 2;                   // 16 nodes per wave
    const int l = lane & 3;                    // lane l holds ch 4l..4l+3
    const int node = (blockIdx.x * 4 + wv) * 16 + g;

    int beg = 0, d = 0;
    if (node < N_NODES) {
        beg = rowptr[node];
        d = deg[node];
        if (beg < 0) beg = 0;
        if (d < 0) d = 0;
        if (beg + d > BINBUF_WORDS) d = BINBUF_WORDS - beg;
    }

    const uint2* hb2 = (const uint2*)hb;       // row = 4 uint2
    float a0 = 0.0f, a1 = 0.0f, a2 = 0.0f, a3 = 0.0f;
    int i = 0;
    if (d >= 8) {
        // prologue: indices for block [0,8)
        unsigned s0 = csr[beg + 0] & 0x1FFFFu, s1 = csr[beg + 1] & 0x1FFFFu;
        unsigned s2 = csr[beg + 2] & 0x1FFFFu, s3 = csr[beg + 3] & 0x1FFFFu;
        unsigned s4 = csr[beg + 4] & 0x1FFFFu, s5 = csr[beg + 5] & 0x1FFFFu;
        unsigned s6 = csr[beg + 6] & 0x1FFFFu, s7 = csr[beg + 7] & 0x1FFFFu;
        for (; i + 16 <= d; i += 8) {
            // issue gathers for current block
            uint2 u0 = hb2[s0 * 4 + l];
            uint2 u1 = hb2[s1 * 4 + l];
            uint2 u2 = hb2[s2 * 4 + l];
            uint2 u3 = hb2[s3 * 4 + l];
            uint2 u4 = hb2[s4 * 4 + l];
            uint2 u5 = hb2[s5 * 4 + l];
            uint2 u6 = hb2[s6 * 4 + l];
            uint2 u7 = hb2[s7 * 4 + l];
            // preload next block's indices (independent of the gathers)
            unsigned n0 = csr[beg + i + 8]  & 0x1FFFFu, n1 = csr[beg + i + 9]  & 0x1FFFFu;
            unsigned n2 = csr[beg + i + 10] & 0x1FFFFu, n3 = csr[beg + i + 11] & 0x1FFFFu;
            unsigned n4 = csr[beg + i + 12] & 0x1FFFFu, n5 = csr[beg + i + 13] & 0x1FFFFu;
            unsigned n6 = csr[beg + i + 14] & 0x1FFFFu, n7 = csr[beg + i + 15] & 0x1FFFFu;
            // consume gathers (csr loads still in flight)
            a0 += __uint_as_float(u0.x << 16);  a1 += __uint_as_float(u0.x & 0xffff0000u);
            a2 += __uint_as_float(u0.y << 16);  a3 += __uint_as_float(u0.y & 0xffff0000u);
            a0 += __uint_as_float(u1.x << 16);  a1 += __uint_as_float(u1.x & 0xffff0000u);
            a2 += __uint_as_float(u1.y << 16);  a3 += __uint_as_float(u1.y & 0xffff0000u);
            a0 += __uint_as_float(u2.x << 16);  a1 += __uint_as_float(u2.x & 0xffff0000u);
            a2 += __uint_as_float(u2.y << 16);  a3 += __uint_as_float(u2.y & 0xffff0000u);
            a0 += __uint_as_float(u3.x << 16);  a1 += __uint_as_float(u3.x & 0xffff0000u);
            a2 += __uint_as_float(u3.y << 16);  a3 += __uint_as_float(u3.y & 0xffff0000u);
            a0 += __uint_as_float(u4.x << 16);  a1 += __uint_as_float(u4.x & 0xffff0000u);
            a2 += __uint_as_float(u4.y << 16);  a3 += __uint_as_float(u4.y & 0xffff0000u);
            a0 += __uint_as_float(u5.x << 16);  a1 += __uint_as_float(u5.x & 0xffff0000u);
            a2 += __uint_as_float(u5.y << 16);  a3 += __uint_as_float(u5.y & 0xffff0000u);
            a0 += __uint_as_float(u6.x << 16);  a1 += __uint_as_float(u6.x & 0xffff0000u);
            a2 += __uint_as_float(u6.y << 16);  a3 += __uint_as_float(u6.y & 0xffff0000u);
            a0 += __uint_as_float(u7.x << 16);  a1 += __uint_as_float(u7.x & 0xffff0000u);
            a2 += __uint_as_float(u7.y << 16);  a3 += __uint_as_float(u7.y & 0xffff0000u);
            s0 = n0; s1 = n1; s2 = n2; s3 = n3; s4 = n4; s5 = n5; s6 = n6; s7 = n7;
        }
        // drain: one guaranteed full block [i, i+8)
        {
            uint2 u0 = hb2[s0 * 4 + l];
            uint2 u1 = hb2[s1 * 4 + l];
            uint2 u2 = hb2[s2 * 4 + l];
            uint2 u3 = hb2[s3 * 4 + l];
            uint2 u4 = hb2[s4 * 4 + l];
            uint2 u5 = hb2[s5 * 4 + l];
            uint2 u6 = hb2[s6 * 4 + l];
            uint2 u7 = hb2[s7 * 4 + l];
            a0 += __uint_as_float(u0.x << 16);  a1 += __uint_as_float(u0.x & 0xffff0000u);
            a2 += __uint_as_float(u0.y << 16);  a3 += __uint_as_float(u0.y & 0xffff0000u);
            a0 += __uint_as_float(u1.x << 16);  a1 += __uint_as_float(u1.x & 0xffff0000u);
            a2 += __uint_as_float(u1.y << 16);  a3 += __uint_as_float(u1.y & 0xffff0000u);
            a0 += __uint_as_float(u2.x << 16);  a1 += __uint_as_float(u2.x & 0xffff0000u);
            a2 += __uint_as_float(u2.y << 16);  a3 += __uint_as_float(u2.y & 0xffff0000u);
            a0 += __uint_as_float(u3.x << 16);  a1 += __uint_as_float(u3.x & 0xffff0000u);
            a2 += __uint_as_float(u3.y << 16);  a3 += __uint_as_float(u3.y & 0xffff0000u);
            a0 += __uint_as_float(u4.x << 16);  a1 += __uint_as_float(u4.x & 0xffff0000u);
            a2 += __uint_as_float(u4.y << 16);  a3 += __uint_as_float(u4.y & 0xffff0000u);
            a0 += __uint_as_float(u5.x << 16);  a1 += __uint_as_float(u5.x & 0xffff0000u);
            a2 += __uint_as_float(u5.y << 16);  a3 += __uint_as_float(u5.y & 0xffff0000u);
            a0 += __uint_as_float(u6.x << 16);  a1 += __uint_as_float(u6.x & 0xffff0000u);
            a2 += __uint_as_float(u6.y << 16);  a3 += __uint_as_float(u6.y & 0xffff0000u);
            a0 += __uint_as_float(u7.x << 16);  a1 += __uint_as_float(u7.x & 0xffff0000u);
            a2 += __uint_as_float(u7.y << 16);  a3 += __uint_as_float(u7.y & 0xffff0000u);
            i += 8;
        }
    }
    for (; i < d; ++i) {
        unsigned s0 = csr[beg + i] & 0x1FFFFu;
        uint2 u0 = hb2[s0 * 4 + l];
        a0 += __uint_as_float(u0.x << 16);  a1 += __uint_as_float(u0.x & 0xffff0000u);
        a2 += __uint_as_float(u0.y << 16);  a3 += __uint_as_float(u0.y & 0xffff0000u);
    }
    float inv = 1.0f / fmaxf((float)d, 1.0f);
    {
        float4 mv; mv.x = a0 * inv; mv.y = a1 * inv; mv.z = a2 * inv; mv.w = a3 * inv;
        *((float4*)(&smean[wv][g][4 * l])) = mv;   // 16B-aligned
    }
    // wave-internal LDS ordering (write then read in program order) — same
    // wave covers all 16 nodes of smean[wv], so no block barrier needed.

    // epilogue: 16 nodes x 8 oc = 128 tasks per wave -> 2 iterations
#pragma unroll
    for (int it = 0; it < 2; ++it) {
        int n8 = (lane >> 3) + 8 * it;         // 0..15
        int oc = lane & 7;
        int gn = (blockIdx.x * 4 + wv) * 16 + n8;
        if (gn < N_NODES) {
            float a = bias[oc];
#pragma unroll
            for (int k = 0; k < HID; ++k)
                a = fmaf(smean[wv][n8][k], W_l[oc * HID + k],
                         fmaf(h_f32[gn * HID + k], W_r[oc * HID + k], a));
            out[gn * OUT_CH + oc] = a;
        }
    }
}

extern "C" void kernel_launch(void* const* d_in, const int* in_sizes, int n_in,
                              void* d_out, int out_size, void* d_ws, size_t ws_size,
                              hipStream_t stream) {
    const float* x    = (const float*)d_in[0];
    const int* eidx   = (const int*)d_in[1];
    const float* W1_l = (const float*)d_in[3];
    const float* b1   = (const float*)d_in[4];
    const float* W1_r = (const float*)d_in[5];
    const float* W2_l = (const float*)d_in[6];
    const float* b2   = (const float*)d_in[7];
    const float* W2_r = (const float*)d_in[8];
    float* out = (float*)d_out;

    const uint4* src4 = (const uint4*)eidx;
    const uint4* dst4 = (const uint4*)(eidx + N_EDGES);

    // Workspace layout (4-byte words), every region written each launch:
    //   binbuf  @ 0           (9,437,184)  1024 bin regions of 8x1152 words
    //   tail    @ 9,437,184   (8,192)      zeroed by prep
    //   xb      @ 9,445,376   (802,816)    bf16 x rows (16 ush = 8 words/row)
    //   hb      @ 10,248,192  (800,000)    bf16 h rows
    //   h_f32   @ 11,048,192  (1,600,000)
    //   rowptr  @ 12,648,192  (100,352)
    //   deg     @ 12,748,544  (100,352)
    // total 12,848,896 words = 51.4 MB
    int*            wsi      = (int*)d_ws;
    unsigned*       binbuf   = (unsigned*)wsi;
    int*            tail     = wsi + 9437184;
    unsigned short* x_bf16   = (unsigned short*)(wsi + 9445376);
    unsigned short* h_bf16   = (unsigned short*)(wsi + 10248192);
    float*          h_f32    = (float*)(wsi + 11048192);
    int*            rowptr   = wsi + 12648192;
    int*            deg      = wsi + 12748544;

    prep_kernel<<<(NBINS * BINW * 16 + 1023) / 1024, 1024, 0, stream>>>(x, x_bf16, tail);
    binfill_kernel<<<N_TILES, BF_THREADS, 0, stream>>>(src4, dst4, tail, binbuf);
    sortagg1_kernel<<<NBINS, 512, 0, stream>>>((const unsigned*)x_bf16, x, binbuf, tail,
                                               rowptr, deg, W1_l, b1, W1_r, h_f32, h_bf16);
    // 64 nodes per block -> covers 100,032 (tail nodes guarded)
    agg2_kernel<<<(N_NODES + 63) / 64, 256, 0, stream>>>((const unsigned*)h_bf16, h_f32, binbuf,
                                          rowptr, deg, W2_l, b2, W2_r, out);
}